// Round 13
// baseline (484.323 us; speedup 1.0000x reference)
//
#include <hip/hip_runtime.h>
#include <math.h>
#include <stdint.h>

typedef __attribute__((ext_vector_type(8))) short short8;
typedef __attribute__((ext_vector_type(4))) float f32x4;

static __device__ __forceinline__ float lrelu(float x) { return x >= 0.f ? x : 0.2f * x; }

// round-to-nearest-even fp32 -> bf16 bits
static __device__ __forceinline__ uint32_t f2bf(float f) {
    uint32_t u = __float_as_uint(f);
    return (u + 0x7FFFu + ((u >> 16) & 1u)) >> 16;
}
static __device__ __forceinline__ float bflo(uint32_t u) { return __uint_as_float(u << 16); }
static __device__ __forceinline__ float bfhi(uint32_t u) { return __uint_as_float(u & 0xFFFF0000u); }

// ---------------- count (XCD-partitioned) + wprep ----------------
__global__ __launch_bounds__(256) void count_wprep(const int* __restrict__ dst, int E, int N,
                                                   int* __restrict__ deg8,
                                                   int* __restrict__ rank, int eb,
                                                   const float* __restrict__ W1,
                                                   const float* __restrict__ W2,
                                                   uint16_t* __restrict__ wtb1,
                                                   uint16_t* __restrict__ wtb2) {
    if ((int)blockIdx.x < eb) {
        int i = blockIdx.x * 256 + threadIdx.x;
        int p = blockIdx.x & 7;
        if (i < E) rank[i] = atomicAdd(&deg8[p * N + dst[i]], 1);
    } else {
        int idx = (blockIdx.x - eb) * 256 + threadIdx.x;   // 0..32767
        const float* src = (idx < 16384) ? W1 : W2;
        uint16_t* dw = (idx < 16384) ? wtb1 : wtb2;
        int j = idx & 16383;
        dw[(j & 127) * 128 + (j >> 7)] = (uint16_t)f2bf(src[j]);  // [col][k]
    }
}

// ---------------- scan1: combine partitions; pad degree+self to mult 16 ----
__global__ __launch_bounds__(256) void scan1(const int* __restrict__ deg8, int N, int ntot,
                                             int* __restrict__ deg,
                                             int* __restrict__ base8,
                                             int* __restrict__ rowptr,
                                             int* __restrict__ csum) {
    __shared__ int s[256];
    int t = threadIdx.x;
    int i = blockIdx.x * 256 + t;
    int v = 0;
    if (i < N) {
        int total = 0;
        #pragma unroll
        for (int p = 0; p < 8; ++p) {
            int c = deg8[p * N + i];
            base8[p * N + i] = total;      // prefix over partitions
            total += c;
        }
        deg[i] = total;
        v = (total + 16) & ~15;            // deg + 1 self edge, padded to 16
    }
    s[t] = v;
    __syncthreads();
    #pragma unroll
    for (int off = 1; off < 256; off <<= 1) {
        int add = (t >= off) ? s[t - off] : 0;
        __syncthreads();
        s[t] += add;
        __syncthreads();
    }
    if (i < ntot) rowptr[i] = s[t] - v;    // exclusive within chunk
    if (t == 255) csum[blockIdx.x] = s[255];
}

__global__ __launch_bounds__(256) void scan2(const int* __restrict__ csum,
                                             int* __restrict__ coff, int nch) {
    __shared__ int s[256];
    int t = threadIdx.x;
    int v = (t < nch) ? csum[t] : 0;
    s[t] = v;
    __syncthreads();
    #pragma unroll
    for (int off = 1; off < 256; off <<= 1) {
        int add = (t >= off) ? s[t - off] : 0;
        __syncthreads();
        s[t] += add;
        __syncthreads();
    }
    coff[t] = s[t] - v;
}

__global__ __launch_bounds__(256) void scan3(int* __restrict__ rowptr,
                                             const int* __restrict__ coff, int ntot) {
    int i = blockIdx.x * 256 + threadIdx.x;
    if (i < ntot) rowptr[i] += coff[blockIdx.x];
}

// Merged fill: blocks [0,eb) scatter edges; blocks [eb,..) write the SELF
// edge at rowptr+deg, sentinels after, plus sentinel as_/h rows.
// hbh is slice-major: 8 regions of (N+1) rows x 8 dwords (32B).
__global__ __launch_bounds__(256) void fill_pad(const int* __restrict__ src,
                                                const int* __restrict__ dst,
                                                const int* __restrict__ rank, int E, int N,
                                                const int* __restrict__ rowptr,
                                                const int* __restrict__ deg,
                                                const int* __restrict__ base8,
                                                uint16_t* __restrict__ colidx,
                                                float* __restrict__ as_,
                                                uint32_t* __restrict__ hbh, int eb) {
    int N1 = N + 1;
    if ((int)blockIdx.x < eb) {
        int i = blockIdx.x * 256 + threadIdx.x;
        int p = blockIdx.x & 7;
        if (i < E) {
            int d = dst[i];
            colidx[rowptr[d] + base8[p * N + d] + rank[i]] = (uint16_t)src[i];
        }
    } else {
        int i = (blockIdx.x - eb) * 256 + threadIdx.x;
        if (i < 4) as_[N * 4 + i] = -1e30f;        // sentinel weight -> exactly 0
        if (i < 64) hbh[(size_t)(i >> 3) * (N1 * 8) + (size_t)N * 8 + (i & 7)] = 0u;
        if (i < N) {
            int b = rowptr[i] + deg[i];
            int e = rowptr[i + 1];
            colidx[b] = (uint16_t)i;               // self edge
            for (int pp = b + 1; pp < e; ++pp) colidx[pp] = (uint16_t)N;
        }
    }
}

// ---------------- MFMA GEMM + alpha ----------------
// h[r,128] = x[r,128] @ W[128,128] via mfma_f32_16x16x32_bf16.
// Epilogue writes bf16 h in SLICE-MAJOR layout (8 slices of 16 cols) so the
// aggregate's per-XCD gather footprint is one 1.6MB slice (L2-resident).
__global__ __launch_bounds__(256) void gemm_mfma(const float* __restrict__ x,
                                                 const uint16_t* __restrict__ wtb,
                                                 const float* __restrict__ a_src,
                                                 const float* __restrict__ a_dst,
                                                 uint32_t* __restrict__ hbh,
                                                 float* __restrict__ as_,
                                                 float* __restrict__ ad_,
                                                 int nrows, int N1) {
    __shared__ __align__(16) char lds[52224];      // xs 64*272 | wsT 128*272
    const int t = threadIdx.x;
    const int row0 = blockIdx.x * 64;

    {   // stage x -> bf16 LDS [64 rows][128 k], row stride 272B
        int r = t >> 2;
        int k16b = (t & 3) * 4;
        const float* xrow = x + (size_t)(row0 + r) * 128;
        bool ok = (row0 + r) < nrows;
        #pragma unroll
        for (int i = 0; i < 4; ++i) {
            int k16 = k16b + i;
            float4 va = make_float4(0.f, 0.f, 0.f, 0.f), vb = va;
            if (ok) {
                va = *(const float4*)(xrow + k16 * 8);
                vb = *(const float4*)(xrow + k16 * 8 + 4);
            }
            uint4 pk;
            pk.x = f2bf(va.x) | (f2bf(va.y) << 16);
            pk.y = f2bf(va.z) | (f2bf(va.w) << 16);
            pk.z = f2bf(vb.x) | (f2bf(vb.y) << 16);
            pk.w = f2bf(vb.z) | (f2bf(vb.w) << 16);
            *(uint4*)(lds + r * 272 + k16 * 16) = pk;
        }
    }
    {   // stage wtb (bf16 [col][k]) -> LDS, row stride 272B
        #pragma unroll
        for (int i = 0; i < 8; ++i) {
            int u = t * 8 + i;
            int col = u >> 4, k16 = u & 15;
            uint4 v = *(const uint4*)(wtb + col * 128 + k16 * 8);
            *(uint4*)(lds + 17408 + col * 272 + k16 * 16) = v;
        }
    }
    __syncthreads();

    const int w = t >> 6, lane = t & 63;
    const int wrow0 = w * 16;
    const int la = lane & 15, lb = lane >> 4;

    f32x4 acc[8];
    #pragma unroll
    for (int ct = 0; ct < 8; ++ct) acc[ct] = (f32x4){0.f, 0.f, 0.f, 0.f};

    const char* xsb = lds + (wrow0 + la) * 272;
    const char* wsb = lds + 17408;
    #pragma unroll
    for (int kc = 0; kc < 4; ++kc) {
        int k16 = kc * 4 + lb;
        short8 a = *(const short8*)(xsb + k16 * 16);
        #pragma unroll
        for (int ct = 0; ct < 8; ++ct) {
            int col = ct * 16 + la;
            short8 b = *(const short8*)(wsb + col * 272 + k16 * 16);
            acc[ct] = __builtin_amdgcn_mfma_f32_16x16x32_bf16(a, b, acc[ct], 0, 0, 0);
        }
    }
    __syncthreads();

    // D lane layout: col = la, row = lb*4 + r2 (within 16-row tile)
    float* scr = (float*)lds;                      // [64][132] f32
    #pragma unroll
    for (int ct = 0; ct < 8; ++ct)
        #pragma unroll
        for (int r2 = 0; r2 < 4; ++r2)
            scr[(wrow0 + lb * 4 + r2) * 132 + ct * 16 + la] = acc[ct][r2];
    __syncthreads();

    {   // final: thread -> (row, head q); pack hbh slices + alpha dots
        int row = t >> 2, q = t & 3;
        int grow = row0 + row;
        float v[32];
        #pragma unroll
        for (int m = 0; m < 8; ++m) {
            float4 f = *(const float4*)(scr + row * 132 + q * 32 + m * 4);
            v[m * 4 + 0] = f.x; v[m * 4 + 1] = f.y;
            v[m * 4 + 2] = f.z; v[m * 4 + 3] = f.w;
        }
        if (grow < nrows) {
            uint4 pk[4];
            #pragma unroll
            for (int m2 = 0; m2 < 4; ++m2) {
                pk[m2].x = f2bf(v[m2 * 8 + 0]) | (f2bf(v[m2 * 8 + 1]) << 16);
                pk[m2].y = f2bf(v[m2 * 8 + 2]) | (f2bf(v[m2 * 8 + 3]) << 16);
                pk[m2].z = f2bf(v[m2 * 8 + 4]) | (f2bf(v[m2 * 8 + 5]) << 16);
                pk[m2].w = f2bf(v[m2 * 8 + 6]) | (f2bf(v[m2 * 8 + 7]) << 16);
            }
            uint32_t* r0 = hbh + (size_t)(2 * q) * (N1 * 8) + (size_t)grow * 8;
            uint32_t* r1 = hbh + (size_t)(2 * q + 1) * (N1 * 8) + (size_t)grow * 8;
            *(uint4*)r0 = pk[0]; *(uint4*)(r0 + 4) = pk[1];
            *(uint4*)r1 = pk[2]; *(uint4*)(r1 + 4) = pk[3];
            float ps = 0.f, pd = 0.f;
            const float* asp = a_src + q * 32;
            const float* adp = a_dst + q * 32;
            #pragma unroll
            for (int j = 0; j < 32; ++j) {
                ps = fmaf(v[j], asp[j], ps);
                pd = fmaf(v[j], adp[j], pd);
            }
            as_[grow * 4 + q] = ps;
            ad_[grow * 4 + q] = pd;
        }
    }
}

// ---------------- slice-parallel aggregation ----------------
// Block b handles slice s = b&7 (round-robins onto XCD s) and 4 nodes (one
// per wave). Slice = 16 bf16 cols (32B) of every node, slice-major storage ->
// per-XCD random-gather footprint = 1.6MB (L2-resident). Self edge is in the
// CSR. Weight exp deduped: lane e(=L&15) computes w(edge e, head s>>1);
// consumers shfl. Lane d=L&7 owns 2 cols; 8 edge-subgroups xor-reduced.
__global__ __launch_bounds__(256) void aggregate(const uint32_t* __restrict__ hbh,
                                                 const float* __restrict__ as_,
                                                 const float* __restrict__ ad_,
                                                 const int* __restrict__ rowptr,
                                                 const uint16_t* __restrict__ colidx,
                                                 const float* __restrict__ bias,
                                                 float* __restrict__ out,
                                                 int n, int N1, int do_elu) {
    int b = blockIdx.x;
    int s = b & 7;                        // slice -> XCD
    int node = (b >> 3) * 4 + (threadIdx.x >> 6);
    if (node >= n) return;
    int h = s >> 1;                       // head of this slice
    int L = threadIdx.x & 63;
    int d = L & 7;                        // dword within 32B slice (2 cols)
    int g = L >> 3;                       // edge subgroup 0..7
    const uint32_t* hb = hbh + (size_t)s * (N1 * 8);
    float adn = ad_[node * 4 + h];
    float ax = 0.f, ay = 0.f, den = 0.f;

    const int beg = rowptr[node], end = rowptr[node + 1];
    for (int j = beg; j < end; j += 16) {
        int ce = __builtin_nontemporal_load(&colidx[j + (L & 15)]);
        float w = __expf(lrelu(as_[ce * 4 + h] + adn));
        int s0 = __shfl(ce, g), s1 = __shfl(ce, 8 + g);
        float w0 = __shfl(w, g), w1 = __shfl(w, 8 + g);
        uint32_t u0 = hb[(size_t)s0 * 8 + d];
        uint32_t u1 = hb[(size_t)s1 * 8 + d];
        ax = fmaf(w0, bflo(u0), ax); ay = fmaf(w0, bfhi(u0), ay);
        ax = fmaf(w1, bflo(u1), ax); ay = fmaf(w1, bfhi(u1), ay);
        den += w0 + w1;
    }
    // combine the 8 edge-subgroup partials (lanes sharing d)
    ax += __shfl_xor(ax, 8);  ax += __shfl_xor(ax, 16);  ax += __shfl_xor(ax, 32);
    ay += __shfl_xor(ay, 8);  ay += __shfl_xor(ay, 16);  ay += __shfl_xor(ay, 32);
    den += __shfl_xor(den, 8); den += __shfl_xor(den, 16); den += __shfl_xor(den, 32);

    if (L < 8) {
        float inv = 1.f / (den + 1e-16f);
        int c = s * 16 + d * 2;
        float o0 = fmaf(ax, inv, bias[c]);
        float o1 = fmaf(ay, inv, bias[c + 1]);
        if (do_elu) {
            o0 = o0 > 0.f ? o0 : (__expf(o0) - 1.f);
            o1 = o1 > 0.f ? o1 : (__expf(o1) - 1.f);
        }
        *(float2*)&out[(size_t)node * 128 + c] = make_float2(o0, o1);
    }
}

extern "C" void kernel_launch(void* const* d_in, const int* in_sizes, int n_in,
                              void* d_out, int out_size, void* d_ws, size_t ws_size,
                              hipStream_t stream) {
    const float* x   = (const float*)d_in[0];
    const int*   ei  = (const int*)d_in[1];
    const float* W1  = (const float*)d_in[2];
    const float* a1s = (const float*)d_in[3];
    const float* a1d = (const float*)d_in[4];
    const float* b1  = (const float*)d_in[5];
    const float* W2  = (const float*)d_in[6];
    const float* a2s = (const float*)d_in[7];
    const float* a2d = (const float*)d_in[8];
    const float* b2  = (const float*)d_in[9];
    float* out = (float*)d_out;

    const int N = in_sizes[0] / 128;   // 50000; N+1 fits uint16 (colidx)
    const int E = in_sizes[1] / 2;
    const int N1 = N + 1;
    const int* esrc = ei;
    const int* edst = ei + E;

    char* w = (char*)d_ws;
    uint32_t* hbh  = (uint32_t*)w; w += (size_t)N1 * 64 * 4;       // slice-major bf16 h
    float*    as_  = (float*)w;    w += (size_t)N1 * 4 * 4;        // +sentinel
    float*    ad_  = (float*)w;    w += (size_t)N1 * 4 * 4;
    int* deg    = (int*)w;   w += (size_t)N * 4;
    int* rowptr = (int*)w;   w += (size_t)N1 * 4;
    int* rank   = (int*)w;   w += (size_t)E * 4;
    int* deg8   = (int*)w;   w += (size_t)8 * N * 4;               // per-XCD counters
    int* base8  = (int*)w;   w += (size_t)8 * N * 4;               // partition prefixes
    int* csum   = (int*)w;   w += 256 * 4;
    int* coff   = (int*)w;   w += 256 * 4;
    uint16_t* wtb1 = (uint16_t*)w; w += 16384 * 2;                 // bf16 W1^T [col][k]
    uint16_t* wtb2 = (uint16_t*)w; w += 16384 * 2;
    w = (char*)(((uintptr_t)w + 31) & ~(uintptr_t)31);             // 32B align
    uint16_t* colidx = (uint16_t*)w; w += ((size_t)E + 16ull * N + 16) * 2; // padded CSR
    float* out1 = out;   // layer-1 output in d_out; consumed by layer-2 gemm
                         // before the final aggregate overwrites d_out

    hipMemsetAsync(deg8, 0, (size_t)8 * N * 4, stream);

    const int eb = (E + 255) / 256;
    const int ntot = N + 1;
    const int nch = (ntot + 255) / 256;
    const int gb = (N + 63) / 64;
    const int nb2 = 8 * ((N + 3) / 4);
    const int pb = (N + 255) / 256;

    count_wprep<<<eb + 128, 256, 0, stream>>>(edst, E, N, deg8, rank, eb,
                                              W1, W2, wtb1, wtb2);
    scan1<<<nch, 256, 0, stream>>>(deg8, N, ntot, deg, base8, rowptr, csum);
    scan2<<<1, 256, 0, stream>>>(csum, coff, nch);
    scan3<<<nch, 256, 0, stream>>>(rowptr, coff, ntot);
    fill_pad<<<eb + pb, 256, 0, stream>>>(esrc, edst, rank, E, N, rowptr, deg,
                                          base8, colidx, as_, hbh, eb);

    // layer 1
    gemm_mfma<<<gb, 256, 0, stream>>>(x, wtb1, a1s, a1d, hbh, as_, ad_, N, N1);
    aggregate<<<nb2, 256, 0, stream>>>(hbh, as_, ad_, rowptr, colidx, b1, out1, N, N1, 1);

    // layer 2
    gemm_mfma<<<gb, 256, 0, stream>>>(out1, wtb2, a2s, a2d, hbh, as_, ad_, N, N1);
    aggregate<<<nb2, 256, 0, stream>>>(hbh, as_, ad_, rowptr, colidx, b2, out, N, N1, 0);
}